// Round 10
// baseline (215.620 us; speedup 1.0000x reference)
//
#include <hip/hip_runtime.h>
#include <hip/hip_bf16.h>

// ---- problem constants ----
#define NN 25000
#define PP 100000
#define TT 4
#define DD 128
#define LEAKY 0.001f

#define PB 32          // propers per block
#define ROWS 128       // PB * TT rows of the MLP per block

typedef __bf16 bf16;
typedef __bf16 bf16x8 __attribute__((ext_vector_type(8)));
typedef float  f32x4  __attribute__((ext_vector_type(4)));
typedef float  f32x2  __attribute__((ext_vector_type(2)));

// ---- workspace layout (bytes) ----
#define OFF_ENCB  0u                    // 25000*128 bf16 = 6,400,000 B
#define OFF_W0SW  6400000u              // 128 chunks * 1KB (fragment order)
#define OFF_W1SW  6531072u              // 32 chunks * 1KB
#define OFF_W2SW  6563840u              // 32 chunks * 1KB
#define OFF_W3SW  6596608u              // 4 chunks * 1KB
#define OFF_WTB   6600704u              // Wt[t][j] = t*W0[512]+b0, 4*128 bf16 = 1024 B
#define OFF_W5B   6601728u              // W0 rows 513..515 as bf16, 3*128 = 768 B
#define OFF_E     6602496u              // 4 tables [NN][128] bf16 = 25,600,000 B
#define WS_END    32202496u

// prep work partition (thread counts)
#define PR_ENCB4 800000
#define PR_W0SW  65536
#define PR_W1SW  16384
#define PR_W2SW  16384
#define PR_W3SW  2048
#define PR_WTB   512
#define PR_W5B   384
#define PR_COPY4 75000
#define PR_TOTAL (PR_ENCB4 + PR_W0SW + PR_W1SW + PR_W2SW + PR_W3SW + PR_WTB + PR_W5B + PR_COPY4)

__global__ __launch_bounds__(256) void prep_kernel(
    const float* __restrict__ encoded, const float* __restrict__ W0,
    const float* __restrict__ W1, const float* __restrict__ W2,
    const float* __restrict__ W3, const float* __restrict__ answer,
    const float* __restrict__ tvec,
    bf16* __restrict__ encB, bf16* __restrict__ W0sw, bf16* __restrict__ W1sw,
    bf16* __restrict__ W2sw, bf16* __restrict__ W3sw, bf16* __restrict__ WtB,
    bf16* __restrict__ W5B, float* __restrict__ out)
{
    int idx = blockIdx.x * 256 + threadIdx.x;
    if (idx < PR_ENCB4) {               // float4 -> 4x bf16 (8 B store)
        float4 v = ((const float4*)encoded)[idx];
        bf16 pk[4] = {(bf16)v.x, (bf16)v.y, (bf16)v.z, (bf16)v.w};
        *(uint2*)(encB + idx * 4) = *(const uint2*)pk;
        return;
    }
    idx -= PR_ENCB4;
    if (idx < PR_W0SW) {
        int j = idx & 7, lane = (idx >> 3) & 63, c = idx >> 9;
        int fr = lane & 15, quad = lane >> 4;
        int kc = c & 15, iwv = c >> 4;
        int k = kc * 32 + quad * 8 + j;
        W0sw[idx] = (bf16)W0[k * 128 + iwv * 16 + fr];
        return;
    }
    idx -= PR_W0SW;
    if (idx < PR_W1SW) {
        int j = idx & 7, lane = (idx >> 3) & 63, c = idx >> 9;
        int fr = lane & 15, quad = lane >> 4;
        int kc = c & 3, nt = c >> 2;
        int k = kc * 32 + quad * 8 + j;
        W1sw[idx] = (bf16)W1[k * 128 + nt * 16 + fr];
        return;
    }
    idx -= PR_W1SW;
    if (idx < PR_W2SW) {
        int j = idx & 7, lane = (idx >> 3) & 63, c = idx >> 9;
        int fr = lane & 15, quad = lane >> 4;
        int kc = c & 3, nt = c >> 2;
        int k = kc * 32 + quad * 8 + j;
        W2sw[idx] = (bf16)W2[k * 128 + nt * 16 + fr];
        return;
    }
    idx -= PR_W2SW;
    if (idx < PR_W3SW) {
        int j = idx & 7, lane = (idx >> 3) & 63, kc = idx >> 9;
        int fr = lane & 15, quad = lane >> 4;
        int k = kc * 32 + quad * 8 + j;
        W3sw[idx] = (fr < 2) ? (bf16)W3[k * 2 + fr] : (bf16)0.0f;
        return;
    }
    idx -= PR_W3SW;
    if (idx < PR_WTB) {                 // Wt[t][j] = t_val*W0[512][j] + b0[j]
        int t = idx >> 7, j = idx & 127;
        // b0 pointer not passed; b0 is folded via W0? -> need b0: it's zeros in
        // setup but stay general: b0 comes in as answer? No — pass via W5B? 
        // We DO have b0: use the extra arg below.
        WtB[idx] = (bf16)(tvec[t] * W0[512 * 128 + j]);
        return;
    }
    idx -= PR_WTB;
    if (idx < PR_W5B) {                 // W0 rows 513,514,515 -> bf16
        W5B[idx] = (bf16)W0[(513 + (idx >> 7)) * 128 + (idx & 127)];
        return;
    }
    idx -= PR_W5B;
    if (idx < PR_COPY4) { ((float4*)out)[idx] = ((const float4*)answer)[idx]; }
}

// E_i[n][j] = sum_k enc[n][k]*W0[i*128+k][j], 128 rows/block (196 blocks):
// W0sw read once per block (25 MB aggregate vs 200 MB at 16 rows/block),
// all 512 threads stage, A-frags hoisted to registers.
__global__ __launch_bounds__(512) void prep_e_kernel(
    const bf16* __restrict__ encB, const bf16* __restrict__ W0sw,
    bf16* __restrict__ E)
{
    __shared__ bf16 sA[128][136];
    const int tid = threadIdx.x;
    const int row0 = blockIdx.x * 128;
    for (int c = tid; c < 2048; c += 512) {      // stage 128 rows x 128 bf16
        int row = c >> 4, seg = c & 15;
        int rr = row0 + row; if (rr >= NN) rr = NN - 1;
        *(bf16x8*)(&sA[row][seg * 8]) =
            *(const bf16x8*)(encB + (size_t)rr * 128 + seg * 8);
    }
    __syncthreads();
    const int wv = tid >> 6, lane = tid & 63;
    const int fr = lane & 15, quad = lane >> 4;
    const bf16* aBase = &sA[wv * 16 + fr][quad * 8];
    bf16x8 aFv[4];
    #pragma unroll
    for (int kcc = 0; kcc < 4; ++kcc) aFv[kcc] = *(const bf16x8*)(aBase + kcc * 32);
    #pragma unroll
    for (int i = 0; i < 4; ++i) {
        #pragma unroll
        for (int nt = 0; nt < 8; ++nt) {
            f32x4 acc = {0.f, 0.f, 0.f, 0.f};
            #pragma unroll
            for (int kcc = 0; kcc < 4; ++kcc) {
                bf16x8 bF = *(const bf16x8*)(W0sw + ((size_t)nt * 16 + i * 4 + kcc) * 512 + lane * 8);
                acc = __builtin_amdgcn_mfma_f32_16x16x32_bf16(aFv[kcc], bF, acc, 0, 0, 0);
            }
            #pragma unroll
            for (int reg = 0; reg < 4; ++reg) {
                int row = row0 + wv * 16 + quad * 4 + reg;
                if (row < NN)
                    E[((size_t)i * NN + row) * 128 + nt * 16 + fr] = (bf16)acc[reg];
            }
        }
    }
}

// Main: E-gather + packed-f32 h0 (Wt/w513..515 as bf16 tables), MFMA layers.
// 5 barriers. LDS ~74 KB -> 2 blocks/CU. (512,4): proven spill-free budget.
__global__ __launch_bounds__(512, 4) void main_kernel(
    const float* __restrict__ coords, const int* __restrict__ propers,
    const float* __restrict__ b0, const float* __restrict__ b1,
    const float* __restrict__ b2, const float* __restrict__ b3,
    const bf16* __restrict__ E, const bf16* __restrict__ W1sw,
    const bf16* __restrict__ W2sw, const bf16* __restrict__ W3sw,
    const bf16* __restrict__ WtB, const bf16* __restrict__ W5B,
    float* __restrict__ out)
{
    __shared__ bf16 sBuf0[ROWS * 136];   // H0 then H2
    __shared__ bf16 sBuf1[ROWS * 136];   // H1
    #define SH0(r, j) sBuf0[(r) * 136 + (j)]
    #define SH1(r, j) sBuf1[(r) * 136 + (j)]
    __shared__ int   sNodes[PB][4];
    __shared__ float sSn[ROWS], sCs[ROWS], sDl[ROWS], sDh[ROWS][3];
    __shared__ float sDelta[ROWS][2];

    const int tid  = threadIdx.x;
    const int pBase = blockIdx.x * PB;

    // ---- phase 1: E gather (all 512) + geometry (tid<128) ----
    const int p  = tid >> 4, s8 = tid & 15;          // 16 threads per proper
    bf16x8 e0, e1, e2, e3;
    {
        int4 pv = *(const int4*)(propers + (pBase + p) * 4);
        if (s8 == 0) { sNodes[p][0] = pv.x; sNodes[p][1] = pv.y;
                       sNodes[p][2] = pv.z; sNodes[p][3] = pv.w; }
        e0 = *(const bf16x8*)(E + ((size_t)0 * NN + pv.x) * 128 + s8 * 8);
        e1 = *(const bf16x8*)(E + ((size_t)1 * NN + pv.y) * 128 + s8 * 8);
        e2 = *(const bf16x8*)(E + ((size_t)2 * NN + pv.z) * 128 + s8 * 8);
        e3 = *(const bf16x8*)(E + ((size_t)3 * NN + pv.w) * 128 + s8 * 8);
    }
    if (tid < ROWS) {
        int r = tid, pp = r >> 2, t = r & 3;
        int4 pv = *(const int4*)(propers + (pBase + pp) * 4);
        const float* c0 = coords + pv.x * 12 + t * 3;
        const float* c1 = coords + pv.y * 12 + t * 3;
        const float* c2 = coords + pv.z * 12 + t * 3;
        const float* c3 = coords + pv.w * 12 + t * 3;
        float u1x = c1[0]-c0[0], u1y = c1[1]-c0[1], u1z = c1[2]-c0[2];
        float u2x = c2[0]-c1[0], u2y = c2[1]-c1[1], u2z = c2[2]-c1[2];
        float u3x = c3[0]-c2[0], u3y = c3[1]-c2[1], u3z = c3[2]-c2[2];
        float ax = u1y*u2z - u1z*u2y, ay = u1z*u2x - u1x*u2z, az = u1x*u2y - u1y*u2x;
        float bx = u2y*u3z - u2z*u3y, by = u2z*u3x - u2x*u3z, bz = u2x*u3y - u2y*u3x;
        float u2n = sqrtf(u2x*u2x + u2y*u2y + u2z*u2z);
        float num = u2n * (u1x*bx + u1y*by + u1z*bz);
        float den = ax*bx + ay*by + az*bz;
        float hyp = sqrtf(num*num + den*den);
        float sn, cs;
        if (hyp > 1e-30f) { float ih = 1.0f / hyp; sn = num * ih; cs = den * ih; }
        else { sn = 0.0f; cs = 1.0f; }
        float drx = c0[0]-c3[0], dry = c0[1]-c3[1], drz = c0[2]-c3[2];
        float dl = sqrtf(fmaxf(drx*drx + dry*dry + drz*drz, 1e-12f));
        float il = 1.0f / dl;
        sSn[r] = sn; sCs[r] = cs; sDl[r] = dl;
        sDh[r][0] = drx * il; sDh[r][1] = dry * il; sDh[r][2] = drz * il;
    }
    __syncthreads();   // B1: geometry ready

    // ---- h0 = leaky(g + Wt[t] + sn*w513 + cs*w514 + dl*w515 + b0) -> SH0 ----
    {
        f32x2 g2[4];
        #pragma unroll
        for (int j2 = 0; j2 < 4; ++j2) {
            g2[j2].x = (float)e0[2*j2]   + (float)e1[2*j2]   + (float)e2[2*j2]   + (float)e3[2*j2];
            g2[j2].y = (float)e0[2*j2+1] + (float)e1[2*j2+1] + (float)e2[2*j2+1] + (float)e3[2*j2+1];
        }
        bf16x8 w3v = *(const bf16x8*)(W5B + 0 * 128 + s8 * 8);
        bf16x8 w4v = *(const bf16x8*)(W5B + 1 * 128 + s8 * 8);
        bf16x8 w5v = *(const bf16x8*)(W5B + 2 * 128 + s8 * 8);
        float b0a = b0[s8 * 8];  // b0 is zeros in this problem; load first lane-block
        // full generality: add per-element b0
        float b0v[8];
        *(float4*)(b0v)     = *(const float4*)(b0 + s8 * 8);
        *(float4*)(b0v + 4) = *(const float4*)(b0 + s8 * 8 + 4);
        (void)b0a;
        #pragma unroll
        for (int t = 0; t < 4; ++t) {
            int r = p * 4 + t;
            bf16x8 wtv = *(const bf16x8*)(WtB + t * 128 + s8 * 8);
            float sn = sSn[r], cs = sCs[r], dl = sDl[r];
            f32x2 snv = {sn, sn}, csv = {cs, cs}, dlv = {dl, dl};
            bf16 hv[8];
            #pragma unroll
            for (int j2 = 0; j2 < 4; ++j2) {
                f32x2 v = g2[j2];
                v += (f32x2){(float)wtv[2*j2] + b0v[2*j2], (float)wtv[2*j2+1] + b0v[2*j2+1]};
                v += snv * (f32x2){(float)w3v[2*j2], (float)w3v[2*j2+1]};
                v += csv * (f32x2){(float)w4v[2*j2], (float)w4v[2*j2+1]};
                v += dlv * (f32x2){(float)w5v[2*j2], (float)w5v[2*j2+1]};
                v.x = fmaxf(v.x, LEAKY * v.x);
                v.y = fmaxf(v.y, LEAKY * v.y);
                hv[2*j2]   = (bf16)v.x;
                hv[2*j2+1] = (bf16)v.y;
            }
            *(bf16x8*)(&SH0(r, s8 * 8)) = *(const bf16x8*)hv;
        }
    }
    __syncthreads();   // B2: H0 ready

    const int wv = tid >> 6, lane = tid & 63;
    const int fr = lane & 15, quad = lane >> 4;
    const int m2 = (wv & 3) * 2;   // first of 2 M-tiles for phases 3/4
    const int nh = wv >> 2;        // N-half (cols nh*64..+63)

    // ---- phase 3: h1 = leaky(h0 @ W1 + b1); read SH0, write SH1 ----
    #pragma unroll
    for (int s = 0; s < 2; ++s) {
        f32x4 hacc[4];
        #pragma unroll
        for (int nt = 0; nt < 4; ++nt) hacc[nt] = (f32x4){0.f,0.f,0.f,0.f};
        const bf16* aRow = &SH0((m2 + s) * 16 + fr, quad * 8);
        const bf16* w1b = W1sw + lane * 8;
        #pragma unroll
        for (int kc = 0; kc < 4; ++kc) {
            bf16x8 aF = *(const bf16x8*)(aRow + kc * 32);
            #pragma unroll
            for (int nt = 0; nt < 4; ++nt) {
                bf16x8 bF = *(const bf16x8*)(w1b + ((nh * 4 + nt) * 4 + kc) * 512);
                hacc[nt] = __builtin_amdgcn_mfma_f32_16x16x32_bf16(aF, bF, hacc[nt], 0, 0, 0);
            }
        }
        #pragma unroll
        for (int nt = 0; nt < 4; ++nt) {
            int j = (nh * 4 + nt) * 16 + fr;
            float bb = b1[j];
            #pragma unroll
            for (int reg = 0; reg < 4; ++reg) {
                int r = (m2 + s) * 16 + quad * 4 + reg;
                float v = hacc[nt][reg] + bb;
                v = fmaxf(v, LEAKY * v);
                SH1(r, j) = (bf16)v;
            }
        }
    }
    __syncthreads();   // B3: H1 ready, H0 reads complete

    // ---- phase 4: h2 = leaky(h1 @ W2 + b2); read SH1, write SH0 ----
    #pragma unroll
    for (int s = 0; s < 2; ++s) {
        f32x4 hacc[4];
        #pragma unroll
        for (int nt = 0; nt < 4; ++nt) hacc[nt] = (f32x4){0.f,0.f,0.f,0.f};
        const bf16* aRow = &SH1((m2 + s) * 16 + fr, quad * 8);
        const bf16* w2b = W2sw + lane * 8;
        #pragma unroll
        for (int kc = 0; kc < 4; ++kc) {
            bf16x8 aF = *(const bf16x8*)(aRow + kc * 32);
            #pragma unroll
            for (int nt = 0; nt < 4; ++nt) {
                bf16x8 bF = *(const bf16x8*)(w2b + ((nh * 4 + nt) * 4 + kc) * 512);
                hacc[nt] = __builtin_amdgcn_mfma_f32_16x16x32_bf16(aF, bF, hacc[nt], 0, 0, 0);
            }
        }
        #pragma unroll
        for (int nt = 0; nt < 4; ++nt) {
            int j = (nh * 4 + nt) * 16 + fr;
            float bb = b2[j];
            #pragma unroll
            for (int reg = 0; reg < 4; ++reg) {
                int r = (m2 + s) * 16 + quad * 4 + reg;
                float v = hacc[nt][reg] + bb;
                v = fmaxf(v, LEAKY * v);
                SH0(r, j) = (bf16)v;
            }
        }
    }
    __syncthreads();   // B4: H2 ready

    // ---- phase 5: delta = h2 @ W3 + b3 (zero-padded to 16 cols); all 8 waves ----
    {
        f32x4 dacc = {0.f,0.f,0.f,0.f};
        const bf16* aRow = &SH0(wv * 16 + fr, quad * 8);
        const bf16* w3b = W3sw + lane * 8;
        #pragma unroll
        for (int kc = 0; kc < 4; ++kc) {
            bf16x8 aF = *(const bf16x8*)(aRow + kc * 32);
            bf16x8 bF = *(const bf16x8*)(w3b + kc * 512);
            dacc = __builtin_amdgcn_mfma_f32_16x16x32_bf16(aF, bF, dacc, 0, 0, 0);
        }
        if (fr < 2) {
            float bb = b3[fr];
            #pragma unroll
            for (int reg = 0; reg < 4; ++reg)
                sDelta[wv * 16 + quad * 4 + reg][fr] = dacc[reg] + bb;
        }
    }
    __syncthreads();   // B5: delta ready

    // ---- phase 6: scatter-add (6 atomics per row, 768 total) ----
    for (int idx = tid; idx < ROWS * 6; idx += 512) {
        int r = idx / 6, c = idx % 6;
        int pp = r >> 2, t = r & 3;
        int side = c / 3, ax = c % 3;
        int node = sNodes[pp][side ? 3 : 0];
        float dval = side ? 0.5f * sDelta[r][1] : -0.5f * sDelta[r][0];
        atomicAdd(out + node * 12 + t * 3 + ax, dval * sDh[r][ax]);
    }
    #undef SH0
    #undef SH1
}

extern "C" void kernel_launch(void* const* d_in, const int* in_sizes, int n_in,
                              void* d_out, int out_size, void* d_ws, size_t ws_size,
                              hipStream_t stream) {
    const float* coords  = (const float*)d_in[0];
    const int*   propers = (const int*)d_in[1];
    const float* encoded = (const float*)d_in[2];
    const float* tvec    = (const float*)d_in[3];
    const float* answer  = (const float*)d_in[4];
    const float* W0 = (const float*)d_in[5];
    const float* b0 = (const float*)d_in[6];
    const float* W1 = (const float*)d_in[7];
    const float* b1 = (const float*)d_in[8];
    const float* W2 = (const float*)d_in[9];
    const float* b2 = (const float*)d_in[10];
    const float* W3 = (const float*)d_in[11];
    const float* b3 = (const float*)d_in[12];
    float* out = (float*)d_out;
    char* ws = (char*)d_ws;
    bf16* encB = (bf16*)(ws + OFF_ENCB);
    bf16* W0sw = (bf16*)(ws + OFF_W0SW);
    bf16* W1sw = (bf16*)(ws + OFF_W1SW);
    bf16* W2sw = (bf16*)(ws + OFF_W2SW);
    bf16* W3sw = (bf16*)(ws + OFF_W3SW);
    bf16* WtB  = (bf16*)(ws + OFF_WTB);
    bf16* W5B  = (bf16*)(ws + OFF_W5B);
    bf16* E    = (bf16*)(ws + OFF_E);

    int prep_blocks = (PR_TOTAL + 255) / 256;
    prep_kernel<<<prep_blocks, 256, 0, stream>>>(encoded, W0, W1, W2, W3, answer, tvec,
                                                 encB, W0sw, W1sw, W2sw, W3sw, WtB, W5B, out);
    prep_e_kernel<<<(NN + 127) / 128, 512, 0, stream>>>(encB, W0sw, E);
    main_kernel<<<PP / PB, 512, 0, stream>>>(coords, propers, b0, b1, b2, b3,
                                             E, W1sw, W2sw, W3sw, WtB, W5B, out);
}

// Round 11
// 195.174 us; speedup vs baseline: 1.1048x; 1.1048x over previous
//
#include <hip/hip_runtime.h>
#include <hip/hip_bf16.h>

// ---- problem constants ----
#define NN 25000
#define PP 100000
#define TT 4
#define DD 128
#define LEAKY 0.001f

#define PB 32          // propers per block
#define ROWS 128       // PB * TT rows of the MLP per block

typedef __bf16 bf16;
typedef __bf16 bf16x8 __attribute__((ext_vector_type(8)));
typedef float  f32x4  __attribute__((ext_vector_type(4)));
typedef float  f32x2  __attribute__((ext_vector_type(2)));

// ---- workspace layout (bytes) ----
#define OFF_ENCB  0u                    // 25000*128 bf16 = 6,400,000 B
#define OFF_W0SW  6400000u              // 128 chunks * 1KB (fragment order)
#define OFF_W1SW  6531072u              // 32 chunks * 1KB
#define OFF_W2SW  6563840u              // 32 chunks * 1KB
#define OFF_W3SW  6596608u              // 4 chunks * 1KB
#define OFF_WTB   6600704u              // Wt[t][j] = t*W0[512]+b0, 4*128 bf16
#define OFF_W5B   6601728u              // W0 rows 513..515 as bf16
#define OFF_E     6602496u              // 4 tables [NN][128] bf16 = 25,600,000 B
#define WS_END    32202496u

// prep work partition (thread counts)
#define PR_ENCB4 800000
#define PR_W0SW  65536
#define PR_W1SW  16384
#define PR_W2SW  16384
#define PR_W3SW  2048
#define PR_WTB   512
#define PR_W5B   384
#define PR_COPY4 75000
#define PR_TOTAL (PR_ENCB4 + PR_W0SW + PR_W1SW + PR_W2SW + PR_W3SW + PR_WTB + PR_W5B + PR_COPY4)

__global__ __launch_bounds__(256) void prep_kernel(
    const float* __restrict__ encoded, const float* __restrict__ W0,
    const float* __restrict__ W1, const float* __restrict__ W2,
    const float* __restrict__ W3, const float* __restrict__ answer,
    const float* __restrict__ tvec, const float* __restrict__ b0,
    bf16* __restrict__ encB, bf16* __restrict__ W0sw, bf16* __restrict__ W1sw,
    bf16* __restrict__ W2sw, bf16* __restrict__ W3sw, bf16* __restrict__ WtB,
    bf16* __restrict__ W5B, float* __restrict__ out)
{
    int idx = blockIdx.x * 256 + threadIdx.x;
    if (idx < PR_ENCB4) {               // float4 -> 4x bf16 (8 B store)
        float4 v = ((const float4*)encoded)[idx];
        bf16 pk[4] = {(bf16)v.x, (bf16)v.y, (bf16)v.z, (bf16)v.w};
        *(uint2*)(encB + idx * 4) = *(const uint2*)pk;
        return;
    }
    idx -= PR_ENCB4;
    if (idx < PR_W0SW) {
        int j = idx & 7, lane = (idx >> 3) & 63, c = idx >> 9;
        int fr = lane & 15, quad = lane >> 4;
        int kc = c & 15, iwv = c >> 4;
        int k = kc * 32 + quad * 8 + j;
        W0sw[idx] = (bf16)W0[k * 128 + iwv * 16 + fr];
        return;
    }
    idx -= PR_W0SW;
    if (idx < PR_W1SW) {
        int j = idx & 7, lane = (idx >> 3) & 63, c = idx >> 9;
        int fr = lane & 15, quad = lane >> 4;
        int kc = c & 3, nt = c >> 2;
        int k = kc * 32 + quad * 8 + j;
        W1sw[idx] = (bf16)W1[k * 128 + nt * 16 + fr];
        return;
    }
    idx -= PR_W1SW;
    if (idx < PR_W2SW) {
        int j = idx & 7, lane = (idx >> 3) & 63, c = idx >> 9;
        int fr = lane & 15, quad = lane >> 4;
        int kc = c & 3, nt = c >> 2;
        int k = kc * 32 + quad * 8 + j;
        W2sw[idx] = (bf16)W2[k * 128 + nt * 16 + fr];
        return;
    }
    idx -= PR_W2SW;
    if (idx < PR_W3SW) {
        int j = idx & 7, lane = (idx >> 3) & 63, kc = idx >> 9;
        int fr = lane & 15, quad = lane >> 4;
        int k = kc * 32 + quad * 8 + j;
        W3sw[idx] = (fr < 2) ? (bf16)W3[k * 2 + fr] : (bf16)0.0f;
        return;
    }
    idx -= PR_W3SW;
    if (idx < PR_WTB) {                 // Wt[t][j] = tvec[t]*W0[512][j] + b0[j]
        int t = idx >> 7, j = idx & 127;
        WtB[idx] = (bf16)(tvec[t] * W0[512 * 128 + j] + b0[j]);
        return;
    }
    idx -= PR_WTB;
    if (idx < PR_W5B) {                 // W0 rows 513,514,515 -> bf16
        W5B[idx] = (bf16)W0[(513 + (idx >> 7)) * 128 + (idx & 127)];
        return;
    }
    idx -= PR_W5B;
    if (idx < PR_COPY4) { ((float4*)out)[idx] = ((const float4*)answer)[idx]; }
}

// E_i[n][j] = sum_k enc[n][k]*W0[i*128+k][j]. Grid 196x4 = 784 blocks (fills
// all 256 CUs — R10's 196-block version under-occupied the GPU). Block
// (rb, ntb): rows rb*128..+127, j-columns ntb*32..+31 (nt in {2*ntb, 2*ntb+1}).
__global__ __launch_bounds__(512) void prep_e_kernel(
    const bf16* __restrict__ encB, const bf16* __restrict__ W0sw,
    bf16* __restrict__ E)
{
    __shared__ bf16 sA[128][136];
    const int tid = threadIdx.x;
    const int row0 = (blockIdx.x >> 2) * 128;
    const int ntb  = blockIdx.x & 3;
    for (int c = tid; c < 2048; c += 512) {      // stage 128 rows x 128 bf16
        int row = c >> 4, seg = c & 15;
        int rr = row0 + row; if (rr >= NN) rr = NN - 1;
        *(bf16x8*)(&sA[row][seg * 8]) =
            *(const bf16x8*)(encB + (size_t)rr * 128 + seg * 8);
    }
    __syncthreads();
    const int wv = tid >> 6, lane = tid & 63;
    const int fr = lane & 15, quad = lane >> 4;
    const bf16* aBase = &sA[wv * 16 + fr][quad * 8];
    bf16x8 aFv[4];
    #pragma unroll
    for (int kcc = 0; kcc < 4; ++kcc) aFv[kcc] = *(const bf16x8*)(aBase + kcc * 32);
    #pragma unroll
    for (int i = 0; i < 4; ++i) {
        #pragma unroll
        for (int ntl = 0; ntl < 2; ++ntl) {
            int nt = ntb * 2 + ntl;
            f32x4 acc = {0.f, 0.f, 0.f, 0.f};
            #pragma unroll
            for (int kcc = 0; kcc < 4; ++kcc) {
                bf16x8 bF = *(const bf16x8*)(W0sw + ((size_t)nt * 16 + i * 4 + kcc) * 512 + lane * 8);
                acc = __builtin_amdgcn_mfma_f32_16x16x32_bf16(aFv[kcc], bF, acc, 0, 0, 0);
            }
            #pragma unroll
            for (int reg = 0; reg < 4; ++reg) {
                int row = row0 + wv * 16 + quad * 4 + reg;
                if (row < NN)
                    E[((size_t)i * NN + row) * 128 + nt * 16 + fr] = (bf16)acc[reg];
            }
        }
    }
}

// Main: E-gather + h0 (hoisted conversions) + MFMA layers; W1 frags
// register-prefetched in phase 1 (drain at B1 together with E loads).
// 5 barriers. LDS ~74 KB -> 2 blocks/CU. (512,4): 128-reg budget.
__global__ __launch_bounds__(512, 4) void main_kernel(
    const float* __restrict__ coords, const int* __restrict__ propers,
    const float* __restrict__ b1, const float* __restrict__ b2,
    const float* __restrict__ b3,
    const bf16* __restrict__ E, const bf16* __restrict__ W1sw,
    const bf16* __restrict__ W2sw, const bf16* __restrict__ W3sw,
    const bf16* __restrict__ WtB, const bf16* __restrict__ W5B,
    float* __restrict__ out)
{
    __shared__ bf16 sBuf0[ROWS * 136];   // H0 then H2
    __shared__ bf16 sBuf1[ROWS * 136];   // H1
    #define SH0(r, j) sBuf0[(r) * 136 + (j)]
    #define SH1(r, j) sBuf1[(r) * 136 + (j)]
    __shared__ int   sNodes[PB][4];
    __shared__ float sSn[ROWS], sCs[ROWS], sDl[ROWS], sDh[ROWS][3];
    __shared__ float sDelta[ROWS][2];

    const int tid  = threadIdx.x;
    const int pBase = blockIdx.x * PB;
    const int wv = tid >> 6, lane = tid & 63;
    const int fr = lane & 15, quad = lane >> 4;
    const int m2 = (wv & 3) * 2;   // first of 2 M-tiles for phases 3/4
    const int nh = wv >> 2;        // N-half (cols nh*64..+63)

    // ---- phase 1: E gather + W1-frag prefetch (all 512) + geometry (tid<128) ----
    const int p  = tid >> 4, s8 = tid & 15;          // 16 threads per proper
    bf16x8 e0, e1, e2, e3;
    {
        int4 pv = *(const int4*)(propers + (pBase + p) * 4);
        if (s8 == 0) { sNodes[p][0] = pv.x; sNodes[p][1] = pv.y;
                       sNodes[p][2] = pv.z; sNodes[p][3] = pv.w; }
        e0 = *(const bf16x8*)(E + ((size_t)0 * NN + pv.x) * 128 + s8 * 8);
        e1 = *(const bf16x8*)(E + ((size_t)1 * NN + pv.y) * 128 + s8 * 8);
        e2 = *(const bf16x8*)(E + ((size_t)2 * NN + pv.z) * 128 + s8 * 8);
        e3 = *(const bf16x8*)(E + ((size_t)3 * NN + pv.w) * 128 + s8 * 8);
    }
    // W1 B-frags for phase 3: 16 x 16B = 64 VGPRs, loaded now so their
    // latency overlaps the E-gather drain at B1.
    bf16x8 w1f[16];
    {
        const bf16* w1b = W1sw + lane * 8;
        #pragma unroll
        for (int nt = 0; nt < 4; ++nt)
            #pragma unroll
            for (int kc = 0; kc < 4; ++kc)
                w1f[nt * 4 + kc] = *(const bf16x8*)(w1b + ((nh * 4 + nt) * 4 + kc) * 512);
    }
    if (tid < ROWS) {
        int r = tid, pp = r >> 2, t = r & 3;
        int4 pv = *(const int4*)(propers + (pBase + pp) * 4);
        const float* c0 = coords + pv.x * 12 + t * 3;
        const float* c1 = coords + pv.y * 12 + t * 3;
        const float* c2 = coords + pv.z * 12 + t * 3;
        const float* c3 = coords + pv.w * 12 + t * 3;
        float u1x = c1[0]-c0[0], u1y = c1[1]-c0[1], u1z = c1[2]-c0[2];
        float u2x = c2[0]-c1[0], u2y = c2[1]-c1[1], u2z = c2[2]-c1[2];
        float u3x = c3[0]-c2[0], u3y = c3[1]-c2[1], u3z = c3[2]-c2[2];
        float ax = u1y*u2z - u1z*u2y, ay = u1z*u2x - u1x*u2z, az = u1x*u2y - u1y*u2x;
        float bx = u2y*u3z - u2z*u3y, by = u2z*u3x - u2x*u3z, bz = u2x*u3y - u2y*u3x;
        float u2n = sqrtf(u2x*u2x + u2y*u2y + u2z*u2z);
        float num = u2n * (u1x*bx + u1y*by + u1z*bz);
        float den = ax*bx + ay*by + az*bz;
        float hyp = sqrtf(num*num + den*den);
        float sn, cs;
        if (hyp > 1e-30f) { float ih = 1.0f / hyp; sn = num * ih; cs = den * ih; }
        else { sn = 0.0f; cs = 1.0f; }
        float drx = c0[0]-c3[0], dry = c0[1]-c3[1], drz = c0[2]-c3[2];
        float dl = sqrtf(fmaxf(drx*drx + dry*dry + drz*drz, 1e-12f));
        float il = 1.0f / dl;
        sSn[r] = sn; sCs[r] = cs; sDl[r] = dl;
        sDh[r][0] = drx * il; sDh[r][1] = dry * il; sDh[r][2] = drz * il;
    }
    __syncthreads();   // B1: geometry + all phase-1 loads drained

    // ---- h0 = leaky(g + Wt[t] + sn*w513 + cs*w514 + dl*w515) -> SH0 ----
    {
        float g[8], w3f[8], w4f[8], w5f[8];
        #pragma unroll
        for (int j = 0; j < 8; ++j)
            g[j] = (float)e0[j] + (float)e1[j] + (float)e2[j] + (float)e3[j];
        bf16x8 w3v = *(const bf16x8*)(W5B + 0 * 128 + s8 * 8);
        bf16x8 w4v = *(const bf16x8*)(W5B + 1 * 128 + s8 * 8);
        bf16x8 w5v = *(const bf16x8*)(W5B + 2 * 128 + s8 * 8);
        #pragma unroll
        for (int j = 0; j < 8; ++j) {   // hoisted: converted ONCE, not per-t
            w3f[j] = (float)w3v[j]; w4f[j] = (float)w4v[j]; w5f[j] = (float)w5v[j];
        }
        #pragma unroll
        for (int t = 0; t < 4; ++t) {
            int r = p * 4 + t;
            bf16x8 wtv = *(const bf16x8*)(WtB + t * 128 + s8 * 8);
            float sn = sSn[r], cs = sCs[r], dl = sDl[r];
            bf16 hv[8];
            #pragma unroll
            for (int j = 0; j < 8; ++j) {
                float v = g[j] + (float)wtv[j] + sn * w3f[j] + cs * w4f[j] + dl * w5f[j];
                v = fmaxf(v, LEAKY * v);
                hv[j] = (bf16)v;
            }
            *(bf16x8*)(&SH0(r, s8 * 8)) = *(const bf16x8*)hv;
        }
    }
    __syncthreads();   // B2: H0 ready

    // ---- phase 3: h1 = leaky(h0 @ W1 + b1); B-frags from registers ----
    #pragma unroll
    for (int s = 0; s < 2; ++s) {
        f32x4 hacc[4];
        #pragma unroll
        for (int nt = 0; nt < 4; ++nt) hacc[nt] = (f32x4){0.f,0.f,0.f,0.f};
        const bf16* aRow = &SH0((m2 + s) * 16 + fr, quad * 8);
        #pragma unroll
        for (int kc = 0; kc < 4; ++kc) {
            bf16x8 aF = *(const bf16x8*)(aRow + kc * 32);
            #pragma unroll
            for (int nt = 0; nt < 4; ++nt)
                hacc[nt] = __builtin_amdgcn_mfma_f32_16x16x32_bf16(aF, w1f[nt * 4 + kc], hacc[nt], 0, 0, 0);
        }
        #pragma unroll
        for (int nt = 0; nt < 4; ++nt) {
            int j = (nh * 4 + nt) * 16 + fr;
            float bb = b1[j];
            #pragma unroll
            for (int reg = 0; reg < 4; ++reg) {
                int r = (m2 + s) * 16 + quad * 4 + reg;
                float v = hacc[nt][reg] + bb;
                v = fmaxf(v, LEAKY * v);
                SH1(r, j) = (bf16)v;
            }
        }
    }
    __syncthreads();   // B3: H1 ready, H0 reads complete

    // ---- phase 4: h2 = leaky(h1 @ W2 + b2); read SH1, write SH0 ----
    #pragma unroll
    for (int s = 0; s < 2; ++s) {
        f32x4 hacc[4];
        #pragma unroll
        for (int nt = 0; nt < 4; ++nt) hacc[nt] = (f32x4){0.f,0.f,0.f,0.f};
        const bf16* aRow = &SH1((m2 + s) * 16 + fr, quad * 8);
        const bf16* w2b = W2sw + lane * 8;
        #pragma unroll
        for (int kc = 0; kc < 4; ++kc) {
            bf16x8 aF = *(const bf16x8*)(aRow + kc * 32);
            #pragma unroll
            for (int nt = 0; nt < 4; ++nt) {
                bf16x8 bF = *(const bf16x8*)(w2b + ((nh * 4 + nt) * 4 + kc) * 512);
                hacc[nt] = __builtin_amdgcn_mfma_f32_16x16x32_bf16(aF, bF, hacc[nt], 0, 0, 0);
            }
        }
        #pragma unroll
        for (int nt = 0; nt < 4; ++nt) {
            int j = (nh * 4 + nt) * 16 + fr;
            float bb = b2[j];
            #pragma unroll
            for (int reg = 0; reg < 4; ++reg) {
                int r = (m2 + s) * 16 + quad * 4 + reg;
                float v = hacc[nt][reg] + bb;
                v = fmaxf(v, LEAKY * v);
                SH0(r, j) = (bf16)v;
            }
        }
    }
    __syncthreads();   // B4: H2 ready

    // ---- phase 5: delta = h2 @ W3 + b3 (zero-padded to 16 cols); all 8 waves ----
    {
        f32x4 dacc = {0.f,0.f,0.f,0.f};
        const bf16* aRow = &SH0(wv * 16 + fr, quad * 8);
        const bf16* w3b = W3sw + lane * 8;
        #pragma unroll
        for (int kc = 0; kc < 4; ++kc) {
            bf16x8 aF = *(const bf16x8*)(aRow + kc * 32);
            bf16x8 bF = *(const bf16x8*)(w3b + kc * 512);
            dacc = __builtin_amdgcn_mfma_f32_16x16x32_bf16(aF, bF, dacc, 0, 0, 0);
        }
        if (fr < 2) {
            float bb = b3[fr];
            #pragma unroll
            for (int reg = 0; reg < 4; ++reg)
                sDelta[wv * 16 + quad * 4 + reg][fr] = dacc[reg] + bb;
        }
    }
    __syncthreads();   // B5: delta ready

    // ---- phase 6: scatter-add (6 atomics per row, 768 total) ----
    for (int idx = tid; idx < ROWS * 6; idx += 512) {
        int r = idx / 6, c = idx % 6;
        int pp = r >> 2, t = r & 3;
        int side = c / 3, ax = c % 3;
        int node = sNodes[pp][side ? 3 : 0];
        float dval = side ? 0.5f * sDelta[r][1] : -0.5f * sDelta[r][0];
        atomicAdd(out + node * 12 + t * 3 + ax, dval * sDh[r][ax]);
    }
    #undef SH0
    #undef SH1
}

extern "C" void kernel_launch(void* const* d_in, const int* in_sizes, int n_in,
                              void* d_out, int out_size, void* d_ws, size_t ws_size,
                              hipStream_t stream) {
    const float* coords  = (const float*)d_in[0];
    const int*   propers = (const int*)d_in[1];
    const float* encoded = (const float*)d_in[2];
    const float* tvec    = (const float*)d_in[3];
    const float* answer  = (const float*)d_in[4];
    const float* W0 = (const float*)d_in[5];
    const float* b0 = (const float*)d_in[6];
    const float* W1 = (const float*)d_in[7];
    const float* b1 = (const float*)d_in[8];
    const float* W2 = (const float*)d_in[9];
    const float* b2 = (const float*)d_in[10];
    const float* W3 = (const float*)d_in[11];
    const float* b3 = (const float*)d_in[12];
    float* out = (float*)d_out;
    char* ws = (char*)d_ws;
    bf16* encB = (bf16*)(ws + OFF_ENCB);
    bf16* W0sw = (bf16*)(ws + OFF_W0SW);
    bf16* W1sw = (bf16*)(ws + OFF_W1SW);
    bf16* W2sw = (bf16*)(ws + OFF_W2SW);
    bf16* W3sw = (bf16*)(ws + OFF_W3SW);
    bf16* WtB  = (bf16*)(ws + OFF_WTB);
    bf16* W5B  = (bf16*)(ws + OFF_W5B);
    bf16* E    = (bf16*)(ws + OFF_E);

    int prep_blocks = (PR_TOTAL + 255) / 256;
    prep_kernel<<<prep_blocks, 256, 0, stream>>>(encoded, W0, W1, W2, W3, answer, tvec, b0,
                                                 encB, W0sw, W1sw, W2sw, W3sw, WtB, W5B, out);
    prep_e_kernel<<<196 * 4, 512, 0, stream>>>(encB, W0sw, E);
    main_kernel<<<PP / PB, 512, 0, stream>>>(coords, propers, b1, b2, b3,
                                             E, W1sw, W2sw, W3sw, WtB, W5B, out);
}